// Round 11
// baseline (39.816 us; speedup 1.0000x reference)
//
#include <hip/hip_runtime.h>
#include <stdint.h>

#define NUM_CLASSES 20
#define BATCH   64
#define CPB     49                      // cells per batch
#define KPB     98                      // candidates per batch
#define NCAND   6272
#define NCHUNK  98                      // 64-candidate chunks
#define NW      8                       // waves per block
#define TPB     512

// monotone float -> sortable u32 (ascending float == ascending u32)
__device__ __forceinline__ unsigned fkey(float f) {
    unsigned u = __float_as_uint(f);
    return (u & 0x80000000u) ? ~u : (u | 0x80000000u);
}

// score of one bbox slice q[0..25): conf * max cls prob, mul-then-max chain
__device__ __forceinline__ float cand_score(const float* q) {
    float conf = q[4];
    float m = __fmul_rn(q[5], conf);
    #pragma unroll
    for (int k = 1; k < NUM_CLASSES; ++k)
        m = fmaxf(m, __fmul_rn(q[5 + k], conf));
    return m;
}

__device__ __forceinline__ float iou_rn(float4 a, float4 b) {
    float xx1 = fmaxf(a.x, b.x), yy1 = fmaxf(a.y, b.y);
    float xx2 = fminf(a.z, b.z), yy2 = fminf(a.w, b.w);
    float w = fmaxf(__fsub_rn(xx2, xx1), 0.0f);
    float h = fmaxf(__fsub_rn(yy2, yy1), 0.0f);
    float inter = __fmul_rn(w, h);
    float aa = __fmul_rn(__fsub_rn(a.z, a.x), __fsub_rn(a.w, a.y));
    float ab = __fmul_rn(__fsub_rn(b.z, b.x), __fsub_rn(b.w, b.y));
    float denom = __fadd_rn(__fsub_rn(__fadd_rn(aa, ab), inter), 1e-9f);
    return __fdiv_rn(inter, denom);
}

// ONE dispatch. Block ib owns output candidates [ib*64, ib*64+64) (<=2 batches).
// Everything (keys, NMS keep, ranks, scatter) recomputed/consumed in-block.
__global__ void __launch_bounds__(TPB) k_all(const float* __restrict__ in,
                                             float* __restrict__ out) {
    __shared__ unsigned vkey32[NCAND];            // compacted valid kLo, idx order
    __shared__ float4   lbox[2][CPB];
    __shared__ int      llab[2][CPB];
    __shared__ float    lscore[2][KPB];
    __shared__ unsigned lkeyLo[2][KPB];
    __shared__ float    lkeep[2][KPB];
    __shared__ unsigned chunkCnt[NCHUNK];
    __shared__ unsigned chunkOff[NCHUNK];
    __shared__ unsigned prefVOwn[64];
    __shared__ unsigned rankPart[NW][64];
    __shared__ unsigned nV_s;
    __shared__ unsigned long long mkey[NW][KPB];
    __shared__ unsigned long long skey[NW][KPB];

    const int tid  = (int)threadIdx.x;
    const int lane = tid & 63;
    const int w    = tid >> 6;
    const int ib   = (int)blockIdx.x;             // 0..97
    const int i0   = ib * 64;
    const int b0   = i0 / KPB;
    const bool need2 = ((i0 + 63) / KPB) > b0;

    if (tid < 2 * KPB) ((float*)lkeep)[tid] = 0.0f;

    // ---- all 6272 keys into registers: reg slot k holds chunk (w + 8k) ----
    unsigned kreg[13];
    #pragma unroll
    for (int k = 0; k < 13; ++k) {
        int ch = w + NW * k;
        if (ch < NCHUNK) {
            int c = ch * 64 + lane;
            const float* q = in + (c >> 1) * 50 + (c & 1) * 25;
            float s = cand_score(q);
            float kf = (s > 0.5f) ? -s : __builtin_inff();
            kreg[k] = fkey(kf);
        } else {
            kreg[k] = 0xFFFFFFFFu;
        }
    }

    // ---- decode own 1-2 batches (boxes/labels/scores/own keys -> LDS) ----
    if (tid < 2 * CPB) {
        int bbD = tid / CPB, cl = tid - bbD * CPB;
        if (bbD == 0 || need2) {
            const float* p = in + ((b0 + bbD) * CPB + cl) * 50;
            float s0 = cand_score(p);
            float s1 = cand_score(p + 25);
            int best = (s1 > s0) ? 1 : 0;         // first-occurrence argmax
            const float* q = p + best * 25;
            int lab = 0; float bv = q[5];
            #pragma unroll
            for (int k = 1; k < NUM_CLASSES; ++k)
                if (q[5 + k] > bv) { bv = q[5 + k]; lab = k; }
            int r = cl / 7, c = cl - r * 7;
            float x  = __fdiv_rn(__fadd_rn(q[0], (float)r), 7.0f);
            float y  = __fdiv_rn(__fadd_rn(q[1], (float)c), 7.0f);
            float hw = __fmul_rn(q[2], 0.5f);
            float hh = __fmul_rn(q[3], 0.5f);
            lbox[bbD][cl] = make_float4(__fsub_rn(x, hw), __fsub_rn(y, hh),
                                        __fadd_rn(x, hw), __fadd_rn(y, hh));
            llab[bbD][cl] = lab + 1;
            lscore[bbD][cl * 2]     = s0;
            lscore[bbD][cl * 2 + 1] = s1;
            lkeyLo[bbD][cl * 2]     = fkey((s0 > 0.5f) ? -s0 : __builtin_inff());
            lkeyLo[bbD][cl * 2 + 1] = fkey((s1 > 0.5f) ? -s1 : __builtin_inff());
        }
    }

    // ---- per-chunk valid counts (ballot) ----
    #pragma unroll
    for (int k = 0; k < 13; ++k) {
        int ch = w + NW * k;
        if (ch < NCHUNK) {
            unsigned long long bal = __ballot(kreg[k] < 0x80000000u);
            if (lane == 0) chunkCnt[ch] = (unsigned)__popcll(bal);
        }
    }
    __syncthreads();                               // B1
    if (tid < NCHUNK) {
        unsigned off = 0;
        for (int t = 0; t < tid; ++t) off += chunkCnt[t];
        chunkOff[tid] = off;
        if (tid == NCHUNK - 1) nV_s = off + chunkCnt[NCHUNK - 1];
    }
    __syncthreads();                               // B2
    // ---- compacted write (index order) + own prefix-valid ----
    #pragma unroll
    for (int k = 0; k < 13; ++k) {
        int ch = w + NW * k;
        if (ch < NCHUNK) {
            bool val = kreg[k] < 0x80000000u;
            unsigned long long bal = __ballot(val);
            unsigned pos = chunkOff[ch] +
                (unsigned)__popcll(bal & ((1ull << lane) - 1ull));
            if (val) vkey32[pos] = kreg[k];
            if (ch == ib) prefVOwn[lane] = pos;    // #valid with idx < own i
        }
    }

    // ---- NMS: 40 (batch,label) tasks, 5 serial per wave; R10-proven body ----
    for (int it = 0; it < 5; ++it) {
        int task = it * NW + w;                    // 0..39
        int bb = task / NUM_CLASSES;
        int L  = task - bb * NUM_CLASSES + 1;
        bool alive = (bb == 0) || need2;
        int base = (b0 + bb) * KPB;
        bool v0 = false, v1 = false;
        unsigned long long key0 = 0, key1 = 0;
        if (alive) {
            unsigned kl0 = lkeyLo[bb][lane];
            v0 = (kl0 < 0x80000000u) && (llab[bb][lane >> 1] == L);
            key0 = ((unsigned long long)kl0 << 32) | (unsigned)(base + lane);
            if (lane + 64 < KPB) {
                unsigned kl1 = lkeyLo[bb][lane + 64];
                v1 = (kl1 < 0x80000000u) && (llab[bb][(lane + 64) >> 1] == L);
                key1 = ((unsigned long long)kl1 << 32) | (unsigned)(base + lane + 64);
            }
        }
        unsigned long long bal0 = __ballot(v0), bal1 = __ballot(v1);
        int n0 = (int)__popcll(bal0);
        int n  = n0 + (int)__popcll(bal1);
        unsigned long long below = (1ull << lane) - 1ull;
        if (v0) mkey[w][__popcll(bal0 & below)] = key0;
        if (v1) mkey[w][n0 + __popcll(bal1 & below)] = key1;
        __syncthreads();                           // mkey visible (uniform count)
        if (n > 0) {
            for (int s = 0; s < 2; ++s) {
                int j = lane + s * 64;
                if (j < n) {
                    unsigned long long kj = mkey[w][j];
                    int rr = 0;
                    for (int i2 = 0; i2 < n; ++i2) rr += (mkey[w][i2] < kj) ? 1 : 0;
                    skey[w][rr] = kj;              // rank-by-count == stable sort
                }
            }
        }
        __syncthreads();                           // skey visible (uniform count)
        if (n > 0) {
            float4 box0 = make_float4(0.f, 0.f, 0.f, 0.f), box1 = box0;
            int t0 = 0, t1 = 0, keep0 = 0, keep1 = 0;
            if (lane < n) {
                t0 = (int)(unsigned)skey[w][lane] - base;
                box0 = lbox[bb][t0 >> 1]; keep0 = 1;
            }
            if (lane + 64 < n) {
                t1 = (int)(unsigned)skey[w][lane + 64] - base;
                box1 = lbox[bb][t1 >> 1]; keep1 = 1;
            }
            for (int g = 0; g < n; ++g) {
                int srcl = g & 63;
                int kg = __shfl((g < 64) ? keep0 : keep1, srcl);
                if (kg) {
                    float4 s4 = (g < 64) ? box0 : box1;
                    float4 bi;
                    bi.x = __shfl(s4.x, srcl); bi.y = __shfl(s4.y, srcl);
                    bi.z = __shfl(s4.z, srcl); bi.w = __shfl(s4.w, srcl);
                    if (keep0 && lane > g)      { if (iou_rn(bi, box0) > 0.3f) keep0 = 0; }
                    if (keep1 && lane + 64 > g) { if (iou_rn(bi, box1) > 0.3f) keep1 = 0; }
                }
            }
            if (keep0) lkeep[bb][t0] = 1.0f;
            if (keep1) lkeep[bb][t1] = 1.0f;
        }
    }
    __syncthreads();                               // B3: vkey32/prefVOwn/lkeep final

    // ---- rank own 64 candidates vs compacted valid keys ----
    const int iG = i0 + lane;
    int bg  = iG / KPB;
    int il  = iG - bg * KPB;
    int bb2 = bg - b0;                             // 0 or 1
    unsigned kiLo = lkeyLo[bb2][il];
    unsigned ci   = prefVOwn[lane];                // compacted pos if valid; #valid<i if not
    {
        unsigned nV = nV_s;
        int cs = ((int)nV + NW - 1) / NW;
        int j0 = w * cs;
        int j1 = min((int)nV, j0 + cs);
        unsigned acc = 0;
        #pragma unroll 8
        for (int j = j0; j < j1; ++j) {
            unsigned kj = vkey32[j];               // wave-uniform broadcast read
            acc += (kj < kiLo) ? 1u : 0u;
            acc += (kj == kiLo && (unsigned)j < ci) ? 1u : 0u;  // stable tie-break
        }
        rankPart[w][lane] = acc;
    }
    __syncthreads();                               // B4
    if (tid < 64) {
        unsigned r;
        if (kiLo < 0x80000000u) {                  // valid: sum partials
            r = 0;
            #pragma unroll
            for (int w2 = 0; w2 < NW; ++w2) r += rankPart[w2][lane];
        } else {                                   // invalid: closed form
            r = nV_s + (unsigned)iG - ci;
        }
        out[r] = (float)bg;                        // batch id
        float4 bx = lbox[bb2][il >> 1];
        *(float4*)(out + NCAND + r * 4) = bx;
        out[NCAND * 5 + r] = (float)llab[bb2][il >> 1];
        out[NCAND * 6 + r] = lscore[bb2][il];
        out[NCAND * 7 + r] = lkeep[bb2][il];
    }
}

extern "C" void kernel_launch(void* const* d_in, const int* in_sizes, int n_in,
                              void* d_out, int out_size, void* d_ws, size_t ws_size,
                              hipStream_t stream) {
    const float* in = (const float*)d_in[0];
    float* out = (float*)d_out;
    k_all<<<NCHUNK, TPB, 0, stream>>>(in, out);
}